// Round 8
// baseline (230.227 us; speedup 1.0000x reference)
//
#include <hip/hip_runtime.h>

// GroupedVectorSA (gfx950) — ROUND 8: cheap bf16 pair-pack (bfe+add3+and_or),
// coalesced LDS-transpose k_prep, pk-pack epilogues everywhere.

typedef __attribute__((ext_vector_type(8))) short bf16x8_t;
typedef __attribute__((ext_vector_type(4))) float f32x4_t;

#define BN_EPS 1e-5f

__device__ __forceinline__ float b2f(unsigned int b) {
    union { unsigned int u; float f; } x; x.u = b << 16; return x.f;
}
__device__ __forceinline__ float blo(unsigned int v) {        // low bf16 of pair
    union { unsigned int u; float f; } x; x.u = v << 16; return x.f;
}
__device__ __forceinline__ float bhi(unsigned int v) {        // high bf16 of pair
    union { unsigned int u; float f; } x; x.u = v & 0xffff0000u; return x.f;
}
__device__ __forceinline__ unsigned int fbits(float f) {
    union { float f; unsigned int u; } x; x.f = f; return x.u;
}
__device__ __forceinline__ unsigned short f2b(float f) {      // RNE fp32->bf16
    unsigned int u = fbits(f);
    return (unsigned short)((u + 0x7fffu + ((u >> 16) & 1u)) >> 16);
}
// RNE pack pair: {lo:a, hi:b}. ~6-8 VALU (bfe+add3 x2, shr, and_or).
__device__ __forceinline__ unsigned int f2bpk(float a, float b) {
    unsigned int ua = fbits(a), ub = fbits(b);
    unsigned int ta = ua + 0x7fffu + ((ua >> 16) & 1u);
    unsigned int tb = ub + 0x7fffu + ((ub >> 16) & 1u);
    return (ta >> 16) | (tb & 0xffff0000u);
}
// relation pair: r = (k-q)*pem+peb on packed bf16 pairs -> packed bf16
__device__ __forceinline__ unsigned int relpair(unsigned int kb, unsigned int qb,
                                                unsigned int pm_, unsigned int pb_) {
    float r0 = (blo(kb) - blo(qb)) * blo(pm_) + blo(pb_);
    float r1 = (bhi(kb) - bhi(qb)) * bhi(pm_) + bhi(pb_);
    return f2bpk(r0, r1);
}

// ---------------------------------------------------------------------------
// K0: 5 fp32 [256][256] weights -> bf16 fragment-linear, via LDS transpose.
// grid = 5*8*4 = 160 blocks (mat, kk, ntq). Coalesced reads AND writes.
// frag-linear: o = nt*4096 + kk*512 + lane*8 + j,
//              value = W[kk*32+(lane>>4)*8+j][nt*16+(lane&15)].
// ---------------------------------------------------------------------------
__global__ __launch_bounds__(256) void k_prep(
    const float* __restrict__ wq, const float* __restrict__ wk,
    const float* __restrict__ wv, const float* __restrict__ pm2,
    const float* __restrict__ pb2, unsigned short* __restrict__ wsT)
{
    __shared__ unsigned short T[32][72];       // 32 k-rows x 64 n-cols (+8 pad)
    const int bid = blockIdx.x;
    const int mat = bid >> 5;
    const int kk  = (bid >> 2) & 7;
    const int ntq = bid & 3;
    const float* s = (mat == 0) ? wq : (mat == 1) ? wk : (mat == 2) ? wv
                     : (mat == 3) ? pm2 : pb2;
    const int t = threadIdx.x;
    {
        int c = t & 63, r0 = t >> 6;
        for (int i = 0; i < 8; ++i) {
            int r = r0 + i * 4;
            T[r][c] = f2b(s[(kk * 32 + r) * 256 + ntq * 64 + c]);
        }
    }
    __syncthreads();
    {
        int seg = t >> 6, lane = t & 63;       // seg = local nt (0..3)
        int col = seg * 16 + (lane & 15);
        int kr  = (lane >> 4) * 8;
        unsigned int v[8];
        #pragma unroll
        for (int j = 0; j < 8; ++j) v[j] = T[kr + j][col];
        uint4 o;
        o.x = v[0] | (v[1] << 16);
        o.y = v[2] | (v[3] << 16);
        o.z = v[4] | (v[5] << 16);
        o.w = v[6] | (v[7] << 16);
        *(uint4*)(wsT + mat * 65536 + (ntq * 4 + seg) * 4096 + kk * 512 + lane * 8) = o;
    }
}

// ---------------------------------------------------------------------------
// K1: q/k/v GEMM. grid=768 (widx = bid>>8, mb = bid&255), blk=256.
// ---------------------------------------------------------------------------
__global__ __launch_bounds__(256) void k_qkv(
    const float* __restrict__ feats,
    const unsigned short* __restrict__ wT,
    const float* __restrict__ bq, const float* __restrict__ bnq,
    const float* __restrict__ bk, const float* __restrict__ bnk,
    const float* __restrict__ bv,
    unsigned short* __restrict__ qkv)
{
    __shared__ unsigned short A[32][264];     // feats tile, then C tile
    const int t    = threadIdx.x;
    const int widx = blockIdx.x >> 8;
    const int mb   = blockIdx.x & 255;

    for (int i = 0; i < 8; ++i) {
        int row = 4 * i + (t >> 6), col = (t & 63) * 4;
        float4 f = *(const float4*)(feats + (mb * 32 + row) * 256 + col);
        *(uint2*)&A[row][col] = make_uint2(f2bpk(f.x, f.y), f2bpk(f.z, f.w));
    }
    __syncthreads();

    const int lane = t & 63, w = t >> 6;
    const int ln15 = lane & 15, quad = lane >> 4;
    const int mt = w & 1, nh = w >> 1;

    bf16x8_t afr[8];
    #pragma unroll
    for (int kk = 0; kk < 8; ++kk)
        afr[kk] = *(const bf16x8_t*)&A[mt * 16 + ln15][kk * 32 + quad * 8];

    const unsigned short* W = wT + widx * 65536;
    const float* bias = (widx == 0) ? bq : (widx == 1) ? bk : bv;
    const float* bn   = (widx == 0) ? bnq : (widx == 1) ? bnk : nullptr;
    unsigned short* dst = qkv + (size_t)widx * 8192 * 256;

    const f32x4_t fzero = {0.f, 0.f, 0.f, 0.f};
    f32x4_t acc[8];
    for (int j = 0; j < 8; ++j) acc[j] = fzero;

    #pragma unroll
    for (int kk = 0; kk < 8; ++kk) {
        #pragma unroll
        for (int j = 0; j < 8; ++j) {
            int nt = nh * 8 + j;
            bf16x8_t bfr = *(const bf16x8_t*)(W + ((nt * 8 + kk) * 64 + lane) * 8);
            acc[j] = __builtin_amdgcn_mfma_f32_16x16x32_bf16(afr[kk], bfr, acc[j], 0, 0, 0);
        }
    }

    float bb[8], sc[8], mu[8], be[8];
    #pragma unroll
    for (int j = 0; j < 8; ++j) {
        int c = (nh * 8 + j) * 16 + ln15;
        bb[j] = bias[c];
        if (bn) {
            sc[j] = bn[c] / sqrtf(bn[768 + c] + BN_EPS);
            be[j] = bn[256 + c];
            mu[j] = bn[512 + c];
        }
    }
    __syncthreads();
    #pragma unroll
    for (int j = 0; j < 8; ++j) {
        int c = (nh * 8 + j) * 16 + ln15;
        float y[4];
        for (int r = 0; r < 4; ++r) {
            y[r] = acc[j][r] + bb[j];
            if (bn) y[r] = fmaxf((y[r] - mu[j]) * sc[j] + be[j], 0.f);
        }
        for (int r = 0; r < 4; r += 2) {
            unsigned int pk = f2bpk(y[r], y[r + 1]);
            A[mt * 16 + quad * 4 + r][c]     = (unsigned short)pk;
            A[mt * 16 + quad * 4 + r + 1][c] = (unsigned short)(pk >> 16);
        }
    }
    __syncthreads();
    {
        int row = t >> 3, cc = (t & 7) * 32;
        #pragma unroll
        for (int j = 0; j < 4; ++j) {
            uint4 v = *(const uint4*)&A[row][cc + 8 * j];
            *(uint4*)(dst + (mb * 32 + row) * 256 + cc + 8 * j) = v;
        }
    }
}

// ---------------------------------------------------------------------------
// K2: fused main. 1 WG = 4 points. blk=256, grid=2048, 2 WG/CU.
// ---------------------------------------------------------------------------
__global__ __launch_bounds__(256, 2) void k_main(
    const float* __restrict__ coords,
    const int*   __restrict__ index,
    const unsigned short* __restrict__ qm,
    const unsigned short* __restrict__ km,
    const unsigned short* __restrict__ vm,
    const unsigned short* __restrict__ pmw2F,
    const unsigned short* __restrict__ pbw2F,
    const float* __restrict__ pm_w1, const float* __restrict__ pm_b1,
    const float* __restrict__ pm_bn, const float* __restrict__ pm_b2,
    const float* __restrict__ pb_w1, const float* __restrict__ pb_b1,
    const float* __restrict__ pb_bn, const float* __restrict__ pb_b2,
    const float* __restrict__ we_w1, const float* __restrict__ we_b1,
    const float* __restrict__ we_bn, const float* __restrict__ we_w2,
    const float* __restrict__ we_b2,
    float* __restrict__ out)
{
    __shared__ unsigned short bufR[64][264];   // h0 -> h1 -> pem -> r
    __shared__ unsigned short bufP[64][264];   // peb
    __shared__ __align__(16) char uni[8448];   // Wpm/Wpb -> we1T/us_/lg_
    float (*Wpm)[256] = (float(*)[256])uni;
    float (*Wpb)[256] = (float(*)[256])(uni + 4096);
    unsigned short (*we1T)[264] = (unsigned short(*)[264])uni;
    float (*us_)[8] = (float(*)[8])(uni + 4224);
    float (*lg_)[8] = (float(*)[8])(uni + 6272);
    __shared__ float posA[64][4];
    __shared__ float bias2[2][256];            // [0]=pb_b2 [1]=pm_b2
    __shared__ float swe[8], dwe[8], web2[8];
    __shared__ float we2s[8][8];

    const int t  = threadIdx.x;
    const int P0 = blockIdx.x * 4;
    const int b  = P0 >> 12;

    // ---- register prefetch: k rows (coalesced, 4 lanes/row) ----
    const int m3  = t >> 2;
    const int Pg3 = P0 + (m3 >> 4);
    const int rg3 = (b << 12) + index[Pg3 * 16 + (m3 & 15)];
    const int c3  = (t & 3) * 8;
    uint4 kpre[8];
    {
        const unsigned short* krow = km + rg3 * 256 + c3;
        #pragma unroll
        for (int i = 0; i < 8; ++i) kpre[i] = *(const uint4*)(krow + 32 * i);
    }
    // ---- register prefetch: v rows (8B/lane per s) ----
    const int p5 = t >> 6, c5 = (t & 63) * 4;
    uint2 vpre[16];
    #pragma unroll
    for (int s = 0; s < 16; ++s) {
        int rgv = (b << 12) + index[(P0 + p5) * 16 + s];
        vpre[s] = *(const uint2*)(vm + rgv * 256 + c5);
    }

    // ---- phase 0: params ----
    if (t < 64) {
        int p = t >> 4, s = t & 15;
        int Pg = P0 + p;
        int rg = (b << 12) + index[Pg * 16 + s];
        posA[t][0] = coords[Pg * 3 + 0] - coords[rg * 3 + 0];
        posA[t][1] = coords[Pg * 3 + 1] - coords[rg * 3 + 1];
        posA[t][2] = coords[Pg * 3 + 2] - coords[rg * 3 + 2];
        posA[t][3] = 0.f;
    }
    {
        int c = t;
        float sc = pm_bn[c] / sqrtf(pm_bn[768 + c] + BN_EPS);
        Wpm[0][c] = pm_w1[c] * sc;
        Wpm[1][c] = pm_w1[256 + c] * sc;
        Wpm[2][c] = pm_w1[512 + c] * sc;
        Wpm[3][c] = (pm_b1[c] - pm_bn[512 + c]) * sc + pm_bn[256 + c];
        sc = pb_bn[c] / sqrtf(pb_bn[768 + c] + BN_EPS);
        Wpb[0][c] = pb_w1[c] * sc;
        Wpb[1][c] = pb_w1[256 + c] * sc;
        Wpb[2][c] = pb_w1[512 + c] * sc;
        Wpb[3][c] = (pb_b1[c] - pb_bn[512 + c]) * sc + pb_bn[256 + c];
        bias2[0][c] = pb_b2[c];
        bias2[1][c] = pm_b2[c];
    }
    if (t < 8) {
        float sc = we_bn[t] / sqrtf(we_bn[24 + t] + BN_EPS);
        swe[t]  = sc;
        dwe[t]  = (we_b1[t] - we_bn[16 + t]) * sc + we_bn[8 + t];
        web2[t] = we_b2[t];
    }
    if (t < 64) we2s[t >> 3][t & 7] = we_w2[t];
    __syncthreads();

    const int lane = t & 63, w = t >> 6;
    const int ln15 = lane & 15, quad = lane >> 4;
    const int mrow = w * 16 + ln15;
    const f32x4_t fzero = {0.f, 0.f, 0.f, 0.f};

    const int hc = (t & 127) * 2;              // h-build col pair
    const int hm0 = (t >> 7) * 32;             // row range

    // ---- h0 (for peb) -> bufR ----
    {
        float w00 = Wpb[0][hc], w01 = Wpb[0][hc + 1];
        float w10 = Wpb[1][hc], w11 = Wpb[1][hc + 1];
        float w20 = Wpb[2][hc], w21 = Wpb[2][hc + 1];
        float w30 = Wpb[3][hc], w31 = Wpb[3][hc + 1];
        for (int i = 0; i < 32; ++i) {
            int m = hm0 + i;
            float4 p = *(const float4*)&posA[m][0];
            float h0 = fmaxf(p.x * w00 + p.y * w10 + p.z * w20 + w30, 0.f);
            float h1 = fmaxf(p.x * w01 + p.y * w11 + p.z * w21 + w31, 0.f);
            *(unsigned int*)&bufR[m][hc] = f2bpk(h0, h1);
        }
    }
    __syncthreads();

    // ---- pass0 MFMA: peb = h0 @ pb_w2 ----
    f32x4_t acc[4][4];
    for (int a = 0; a < 4; ++a) for (int mt = 0; mt < 4; ++mt) acc[a][mt] = fzero;
    #pragma unroll
    for (int kk = 0; kk < 8; ++kk) {
        bf16x8_t afr[4];
        #pragma unroll
        for (int mt = 0; mt < 4; ++mt)
            afr[mt] = *(const bf16x8_t*)&bufR[mt * 16 + ln15][kk * 32 + quad * 8];
        #pragma unroll
        for (int ntl = 0; ntl < 4; ++ntl) {
            int nt = w * 4 + ntl;
            bf16x8_t bfr = *(const bf16x8_t*)(pbw2F + ((nt * 8 + kk) * 64 + lane) * 8);
            #pragma unroll
            for (int mt = 0; mt < 4; ++mt)
                acc[ntl][mt] = __builtin_amdgcn_mfma_f32_16x16x32_bf16(afr[mt], bfr, acc[ntl][mt], 0, 0, 0);
        }
    }
    __syncthreads();                           // h0 reads done -> bufR reusable
    // peb epilogue -> bufP (pk-pack pairs over r)
    #pragma unroll
    for (int ntl = 0; ntl < 4; ++ntl) {
        int c = (w * 4 + ntl) * 16 + ln15;
        float bb = bias2[0][c];
        for (int mt = 0; mt < 4; ++mt)
            for (int r = 0; r < 4; r += 2) {
                unsigned int pk = f2bpk(acc[ntl][mt][r] + bb, acc[ntl][mt][r + 1] + bb);
                bufP[mt * 16 + quad * 4 + r][c]     = (unsigned short)pk;
                bufP[mt * 16 + quad * 4 + r + 1][c] = (unsigned short)(pk >> 16);
            }
    }
    // h1 (for pem) -> bufR
    {
        float w00 = Wpm[0][hc], w01 = Wpm[0][hc + 1];
        float w10 = Wpm[1][hc], w11 = Wpm[1][hc + 1];
        float w20 = Wpm[2][hc], w21 = Wpm[2][hc + 1];
        float w30 = Wpm[3][hc], w31 = Wpm[3][hc + 1];
        for (int i = 0; i < 32; ++i) {
            int m = hm0 + i;
            float4 p = *(const float4*)&posA[m][0];
            float h0 = fmaxf(p.x * w00 + p.y * w10 + p.z * w20 + w30, 0.f);
            float h1 = fmaxf(p.x * w01 + p.y * w11 + p.z * w21 + w31, 0.f);
            *(unsigned int*)&bufR[m][hc] = f2bpk(h0, h1);
        }
    }
    __syncthreads();

    // ---- pass1 MFMA: pem = h1 @ pm_w2 ----
    for (int a = 0; a < 4; ++a) for (int mt = 0; mt < 4; ++mt) acc[a][mt] = fzero;
    #pragma unroll
    for (int kk = 0; kk < 8; ++kk) {
        bf16x8_t afr[4];
        #pragma unroll
        for (int mt = 0; mt < 4; ++mt)
            afr[mt] = *(const bf16x8_t*)&bufR[mt * 16 + ln15][kk * 32 + quad * 8];
        #pragma unroll
        for (int ntl = 0; ntl < 4; ++ntl) {
            int nt = w * 4 + ntl;
            bf16x8_t bfr = *(const bf16x8_t*)(pmw2F + ((nt * 8 + kk) * 64 + lane) * 8);
            #pragma unroll
            for (int mt = 0; mt < 4; ++mt)
                acc[ntl][mt] = __builtin_amdgcn_mfma_f32_16x16x32_bf16(afr[mt], bfr, acc[ntl][mt], 0, 0, 0);
        }
    }
    __syncthreads();                           // h1 reads done
    // pem epilogue -> bufR
    #pragma unroll
    for (int ntl = 0; ntl < 4; ++ntl) {
        int c = (w * 4 + ntl) * 16 + ln15;
        float bb = bias2[1][c];
        for (int mt = 0; mt < 4; ++mt)
            for (int r = 0; r < 4; r += 2) {
                unsigned int pk = f2bpk(acc[ntl][mt][r] + bb, acc[ntl][mt][r + 1] + bb);
                bufR[mt * 16 + quad * 4 + r][c]     = (unsigned short)pk;
                bufR[mt * 16 + quad * 4 + r + 1][c] = (unsigned short)(pk >> 16);
            }
    }
    __syncthreads();

    // ---- phase 3: r = (k - q) * pem + peb ; we1T fill ----
    if (t < 64) {
        int g = t >> 3, j8 = t & 7;
        for (int i = 0; i < 32; ++i) {
            int c = j8 * 32 + i;
            we1T[g][c] = f2b(we_w1[c * 8 + g]);
        }
    }
    {
        const unsigned short* qrow = qm + Pg3 * 256 + c3;
        #pragma unroll
        for (int i = 0; i < 8; ++i) {
            int c = c3 + 32 * i;
            uint4 qb  = *(const uint4*)(qrow + 32 * i);
            uint4 pmv = *(const uint4*)&bufR[m3][c];
            uint4 pbv = *(const uint4*)&bufP[m3][c];
            uint4 r;
            r.x = relpair(kpre[i].x, qb.x, pmv.x, pbv.x);
            r.y = relpair(kpre[i].y, qb.y, pmv.y, pbv.y);
            r.z = relpair(kpre[i].z, qb.z, pmv.z, pbv.z);
            r.w = relpair(kpre[i].w, qb.w, pmv.w, pbv.w);
            *(uint4*)&bufR[m3][c] = r;
        }
    }
    __syncthreads();

    // ---- phase 4a: logits GEMM ----
    {
        const bf16x8_t bz = {0, 0, 0, 0, 0, 0, 0, 0};
        f32x4_t lacc = fzero;
        #pragma unroll
        for (int kk = 0; kk < 8; ++kk) {
            bf16x8_t afr = *(const bf16x8_t*)&bufR[mrow][kk * 32 + quad * 8];
            bf16x8_t bfr = bz;
            if (ln15 < 8) bfr = *(const bf16x8_t*)&we1T[ln15][kk * 32 + quad * 8];
            lacc = __builtin_amdgcn_mfma_f32_16x16x32_bf16(afr, bfr, lacc, 0, 0, 0);
        }
        if (ln15 < 8) {
            float sc = swe[ln15], dd = dwe[ln15];
            for (int r = 0; r < 4; ++r)
                us_[w * 16 + quad * 4 + r][ln15] = fmaxf(lacc[r] * sc + dd, 0.f);
        }
    }
    __syncthreads();

    // ---- phase 4b ----
    if (t < 64) {
        float uv[8];
        for (int gp = 0; gp < 8; ++gp) uv[gp] = us_[t][gp];
        for (int g = 0; g < 8; ++g) {
            float l = web2[g];
            for (int gp = 0; gp < 8; ++gp) l += uv[gp] * we2s[gp][g];
            lg_[t][g] = l;
        }
    }
    __syncthreads();

    // ---- phase 4c: softmax ----
    if (t < 32) {
        int p = t >> 3, g = t & 7;
        float mx = -1e30f;
        for (int s = 0; s < 16; ++s) mx = fmaxf(mx, lg_[p * 16 + s][g]);
        float e[16], sum = 0.f;
        for (int s = 0; s < 16; ++s) { e[s] = __expf(lg_[p * 16 + s][g] - mx); sum += e[s]; }
        float inv = 1.f / sum;
        for (int s = 0; s < 16; ++s) lg_[p * 16 + s][g] = e[s] * inv;
    }
    __syncthreads();

    // ---- phase 5: out (v prefetched) ----
    {
        int g = c5 >> 5;
        float a0 = 0.f, a1 = 0.f, a2 = 0.f, a3 = 0.f;
        #pragma unroll
        for (int s = 0; s < 16; ++s) {
            int m = p5 * 16 + s;
            float wv_ = lg_[m][g];
            uint2 v4 = vpre[s];
            uint2 p4 = *(const uint2*)&bufP[m][c5];
            a0 += wv_ * (blo(v4.x) + blo(p4.x));
            a1 += wv_ * (bhi(v4.x) + bhi(p4.x));
            a2 += wv_ * (blo(v4.y) + blo(p4.y));
            a3 += wv_ * (bhi(v4.y) + bhi(p4.y));
        }
        *(float4*)(out + (size_t)(P0 + p5) * 256 + c5) = make_float4(a0, a1, a2, a3);
    }
}

// ---------------------------------------------------------------------------
extern "C" void kernel_launch(void* const* d_in, const int* in_sizes, int n_in,
                              void* d_out, int out_size, void* d_ws, size_t ws_size,
                              hipStream_t stream)
{
    const float* feats  = (const float*)d_in[0];
    const float* coords = (const float*)d_in[1];
    const int*   index  = (const int*)d_in[2];
    const float* wq     = (const float*)d_in[3];
    const float* bq     = (const float*)d_in[4];
    const float* bnq    = (const float*)d_in[5];
    const float* wk     = (const float*)d_in[6];
    const float* bk     = (const float*)d_in[7];
    const float* bnk    = (const float*)d_in[8];
    const float* wv     = (const float*)d_in[9];
    const float* bv     = (const float*)d_in[10];
    const float* pm_w1  = (const float*)d_in[11];
    const float* pm_b1  = (const float*)d_in[12];
    const float* pm_bn  = (const float*)d_in[13];
    const float* pm_w2  = (const float*)d_in[14];
    const float* pm_b2  = (const float*)d_in[15];
    const float* pb_w1  = (const float*)d_in[16];
    const float* pb_b1  = (const float*)d_in[17];
    const float* pb_bn  = (const float*)d_in[18];
    const float* pb_w2  = (const float*)d_in[19];
    const float* pb_b2  = (const float*)d_in[20];
    const float* we_w1  = (const float*)d_in[21];
    const float* we_b1  = (const float*)d_in[22];
    const float* we_bn  = (const float*)d_in[23];
    const float* we_w2  = (const float*)d_in[24];
    const float* we_b2  = (const float*)d_in[25];

    unsigned short* qkv = (unsigned short*)d_ws;
    unsigned short* wsT = qkv + (size_t)3 * 8192 * 256;

    const size_t need = ((size_t)3 * 8192 * 256 + (size_t)5 * 65536) * 2;
    if (ws_size < need) {
        hipMemsetAsync(d_out, 0, (size_t)out_size * 4, stream);
        return;
    }

    k_prep<<<160,  256, 0, stream>>>(wq, wk, wv, pm_w2, pb_w2, wsT);
    k_qkv <<<768,  256, 0, stream>>>(feats, wsT, bq, bnq, bk, bnk, bv, qkv);
    k_main<<<2048, 256, 0, stream>>>(coords, index,
                                     qkv,
                                     qkv + (size_t)8192 * 256,
                                     qkv + (size_t)2 * 8192 * 256,
                                     wsT + 3 * 65536,
                                     wsT + 4 * 65536,
                                     pm_w1, pm_b1, pm_bn, pm_b2,
                                     pb_w1, pb_b1, pb_bn, pb_b2,
                                     we_w1, we_b1, we_bn, we_w2, we_b2,
                                     (float*)d_out);
}

// Round 9
// 206.053 us; speedup vs baseline: 1.1173x; 1.1173x over previous
//
#include <hip/hip_runtime.h>

// GroupedVectorSA (gfx950) — ROUND 9: hybrid per-wave/cooperative k_main.
// Cooperative M=64 MFMA passes (B-reuse), per-wave everything else (5 barriers),
// relation fused into logits in registers, folds precomputed in k_prep.

typedef __attribute__((ext_vector_type(8))) short bf16x8_t;
typedef __attribute__((ext_vector_type(4))) float f32x4_t;

#define BN_EPS 1e-5f
#define WSYNC() asm volatile("s_waitcnt lgkmcnt(0)" ::: "memory")

__device__ __forceinline__ float blo(unsigned int v) {
    union { unsigned int u; float f; } x; x.u = v << 16; return x.f;
}
__device__ __forceinline__ float bhi(unsigned int v) {
    union { unsigned int u; float f; } x; x.u = v & 0xffff0000u; return x.f;
}
__device__ __forceinline__ unsigned int fbits(float f) {
    union { float f; unsigned int u; } x; x.f = f; return x.u;
}
__device__ __forceinline__ unsigned short f2b(float f) {      // RNE fp32->bf16
    unsigned int u = fbits(f);
    return (unsigned short)((u + 0x7fffu + ((u >> 16) & 1u)) >> 16);
}
__device__ __forceinline__ unsigned int f2bpk(float a, float b) {
    unsigned int ua = fbits(a), ub = fbits(b);
    unsigned int ta = ua + 0x7fffu + ((ua >> 16) & 1u);
    unsigned int tb = ub + 0x7fffu + ((ub >> 16) & 1u);
    return (ta >> 16) | (tb & 0xffff0000u);
}
__device__ __forceinline__ unsigned int relpair(unsigned int kb, unsigned int qb,
                                                unsigned int pm_, unsigned int pb_) {
    float r0 = (blo(kb) - blo(qb)) * blo(pm_) + blo(pb_);
    float r1 = (bhi(kb) - bhi(qb)) * bhi(pm_) + bhi(pb_);
    return f2bpk(r0, r1);
}

// ---------------------------------------------------------------------------
// K0: blocks 0..159: 5 weights -> bf16 fragment-linear (LDS transpose).
//     block 160: folded pos-MLP layer-1 coeffs -> W4 (float4 per col; [0:256)=pm,
//                [256:512)=pb).   block 161: we_w1^T bf16 [8][256] -> we1TF.
// ---------------------------------------------------------------------------
__global__ __launch_bounds__(256) void k_prep(
    const float* __restrict__ wq, const float* __restrict__ wk,
    const float* __restrict__ wv, const float* __restrict__ pm2,
    const float* __restrict__ pb2,
    const float* __restrict__ pm_w1, const float* __restrict__ pm_b1,
    const float* __restrict__ pm_bn,
    const float* __restrict__ pb_w1, const float* __restrict__ pb_b1,
    const float* __restrict__ pb_bn,
    const float* __restrict__ we_w1,
    unsigned short* __restrict__ wsT, float* __restrict__ W4,
    unsigned short* __restrict__ we1TF)
{
    const int bid = blockIdx.x, t = threadIdx.x;
    if (bid < 160) {
        __shared__ unsigned short T[32][72];
        const int mat = bid >> 5;
        const int kk  = (bid >> 2) & 7;
        const int ntq = bid & 3;
        const float* s = (mat == 0) ? wq : (mat == 1) ? wk : (mat == 2) ? wv
                         : (mat == 3) ? pm2 : pb2;
        {
            int c = t & 63, r0 = t >> 6;
            for (int i = 0; i < 8; ++i) {
                int r = r0 + i * 4;
                T[r][c] = f2b(s[(kk * 32 + r) * 256 + ntq * 64 + c]);
            }
        }
        __syncthreads();
        {
            int seg = t >> 6, lane = t & 63;
            int col = seg * 16 + (lane & 15);
            int kr  = (lane >> 4) * 8;
            unsigned int v[8];
            #pragma unroll
            for (int j = 0; j < 8; ++j) v[j] = T[kr + j][col];
            uint4 o;
            o.x = v[0] | (v[1] << 16);
            o.y = v[2] | (v[3] << 16);
            o.z = v[4] | (v[5] << 16);
            o.w = v[6] | (v[7] << 16);
            *(uint4*)(wsT + mat * 65536 + (ntq * 4 + seg) * 4096 + kk * 512 + lane * 8) = o;
        }
    } else if (bid == 160) {
        int c = t;
        float s = pm_bn[c] / sqrtf(pm_bn[768 + c] + BN_EPS);
        float4 wm = make_float4(pm_w1[c] * s, pm_w1[256 + c] * s, pm_w1[512 + c] * s,
                                (pm_b1[c] - pm_bn[512 + c]) * s + pm_bn[256 + c]);
        s = pb_bn[c] / sqrtf(pb_bn[768 + c] + BN_EPS);
        float4 wb = make_float4(pb_w1[c] * s, pb_w1[256 + c] * s, pb_w1[512 + c] * s,
                                (pb_b1[c] - pb_bn[512 + c]) * s + pb_bn[256 + c]);
        ((float4*)W4)[c]       = wm;
        ((float4*)W4)[256 + c] = wb;
    } else {
        for (int j = 0; j < 8; ++j) {
            int e = t * 8 + j;
            int g = e >> 8, c = e & 255;
            we1TF[g * 256 + c] = f2b(we_w1[c * 8 + g]);
        }
    }
}

// ---------------------------------------------------------------------------
// K1: q/k/v GEMM. grid=768 (widx = bid>>8, mb = bid&255), blk=256.
// ---------------------------------------------------------------------------
__global__ __launch_bounds__(256) void k_qkv(
    const float* __restrict__ feats,
    const unsigned short* __restrict__ wT,
    const float* __restrict__ bq, const float* __restrict__ bnq,
    const float* __restrict__ bk, const float* __restrict__ bnk,
    const float* __restrict__ bv,
    unsigned short* __restrict__ qkv)
{
    __shared__ unsigned short A[32][264];
    const int t    = threadIdx.x;
    const int widx = blockIdx.x >> 8;
    const int mb   = blockIdx.x & 255;

    for (int i = 0; i < 8; ++i) {
        int row = 4 * i + (t >> 6), col = (t & 63) * 4;
        float4 f = *(const float4*)(feats + (mb * 32 + row) * 256 + col);
        *(uint2*)&A[row][col] = make_uint2(f2bpk(f.x, f.y), f2bpk(f.z, f.w));
    }
    __syncthreads();

    const int lane = t & 63, w = t >> 6;
    const int ln15 = lane & 15, quad = lane >> 4;
    const int mt = w & 1, nh = w >> 1;

    bf16x8_t afr[8];
    #pragma unroll
    for (int kk = 0; kk < 8; ++kk)
        afr[kk] = *(const bf16x8_t*)&A[mt * 16 + ln15][kk * 32 + quad * 8];

    const unsigned short* W = wT + widx * 65536;
    const float* bias = (widx == 0) ? bq : (widx == 1) ? bk : bv;
    const float* bn   = (widx == 0) ? bnq : (widx == 1) ? bnk : nullptr;
    unsigned short* dst = qkv + (size_t)widx * 8192 * 256;

    const f32x4_t fzero = {0.f, 0.f, 0.f, 0.f};
    f32x4_t acc[8];
    for (int j = 0; j < 8; ++j) acc[j] = fzero;

    #pragma unroll
    for (int kk = 0; kk < 8; ++kk) {
        #pragma unroll
        for (int j = 0; j < 8; ++j) {
            int nt = nh * 8 + j;
            bf16x8_t bfr = *(const bf16x8_t*)(W + ((nt * 8 + kk) * 64 + lane) * 8);
            acc[j] = __builtin_amdgcn_mfma_f32_16x16x32_bf16(afr[kk], bfr, acc[j], 0, 0, 0);
        }
    }

    float bb[8], sc[8], mu[8], be[8];
    #pragma unroll
    for (int j = 0; j < 8; ++j) {
        int c = (nh * 8 + j) * 16 + ln15;
        bb[j] = bias[c];
        if (bn) {
            sc[j] = bn[c] / sqrtf(bn[768 + c] + BN_EPS);
            be[j] = bn[256 + c];
            mu[j] = bn[512 + c];
        }
    }
    __syncthreads();
    #pragma unroll
    for (int j = 0; j < 8; ++j) {
        int c = (nh * 8 + j) * 16 + ln15;
        float y[4];
        for (int r = 0; r < 4; ++r) {
            y[r] = acc[j][r] + bb[j];
            if (bn) y[r] = fmaxf((y[r] - mu[j]) * sc[j] + be[j], 0.f);
        }
        for (int r = 0; r < 4; r += 2) {
            unsigned int pk = f2bpk(y[r], y[r + 1]);
            A[mt * 16 + quad * 4 + r][c]     = (unsigned short)pk;
            A[mt * 16 + quad * 4 + r + 1][c] = (unsigned short)(pk >> 16);
        }
    }
    __syncthreads();
    {
        int row = t >> 3, cc = (t & 7) * 32;
        #pragma unroll
        for (int j = 0; j < 4; ++j) {
            uint4 v = *(const uint4*)&A[row][cc + 8 * j];
            *(uint4*)(dst + (mb * 32 + row) * 256 + cc + 8 * j) = v;
        }
    }
}

// ---------------------------------------------------------------------------
// K2: fused main. 1 WG = 4 points, wave w owns point w. blk=256, grid=2048.
// Cooperative MFMA passes (5 barriers); everything else wave-synchronous.
// ---------------------------------------------------------------------------
__global__ __launch_bounds__(256, 2) void k_main(
    const float* __restrict__ coords,
    const int*   __restrict__ index,
    const unsigned short* __restrict__ qm,
    const unsigned short* __restrict__ km,
    const unsigned short* __restrict__ vm,
    const unsigned short* __restrict__ pmw2F,
    const unsigned short* __restrict__ pbw2F,
    const float* __restrict__ W4,
    const unsigned short* __restrict__ we1TF,
    const float* __restrict__ pm_b2, const float* __restrict__ pb_b2,
    const float* __restrict__ we_b1, const float* __restrict__ we_bn,
    const float* __restrict__ we_w2, const float* __restrict__ we_b2,
    float* __restrict__ out)
{
    __shared__ unsigned short bufR[64][264];   // h0 -> h1 -> pem
    __shared__ unsigned short bufP[64][264];   // peb
    __shared__ float posA[64][4];
    __shared__ float us_[64][8];               // u -> logits -> softmax w
    __shared__ int   rowg_[64];
    __shared__ float we2s[8][8];
    __shared__ float web2[8];

    const int t  = threadIdx.x;
    const int P0 = blockIdx.x * 4;
    const int bb_ = P0 >> 12;
    const int w = t >> 6, lane = t & 63;
    const int ln15 = lane & 15, quad = lane >> 4;
    const int R0 = w * 16;
    const int Pg = P0 + w;

    // ---- per-lane neighbor row (s = ln15) + k prefetch in A-frag layout ----
    const int rg = (bb_ << 12) + index[Pg * 16 + ln15];
    uint4 kpre[8];
    #pragma unroll
    for (int kk = 0; kk < 8; ++kk)
        kpre[kk] = *(const uint4*)(km + rg * 256 + kk * 32 + quad * 8);

    // ---- per-lane folded layer-1 coeffs (4 cols) ----
    const int hc = lane * 4;
    float4 cm[4], cb[4];
    #pragma unroll
    for (int i = 0; i < 4; ++i) {
        cm[i] = ((const float4*)W4)[hc + i];
        cb[i] = ((const float4*)W4)[256 + hc + i];
    }

    // ---- per-lane logits-BN fold ----
    const int g8 = ln15 & 7;
    const float swe_r = we_bn[g8] / sqrtf(we_bn[24 + g8] + BN_EPS);
    const float dwe_r = (we_b1[g8] - we_bn[16 + g8]) * swe_r + we_bn[8 + g8];

    // ---- per-wave staging: pos + rowg (lanes<16); we2s/web2 (block) ----
    if (lane < 16) {
        rowg_[R0 + lane] = rg;
        posA[R0 + lane][0] = coords[Pg * 3 + 0] - coords[rg * 3 + 0];
        posA[R0 + lane][1] = coords[Pg * 3 + 1] - coords[rg * 3 + 1];
        posA[R0 + lane][2] = coords[Pg * 3 + 2] - coords[rg * 3 + 2];
        posA[R0 + lane][3] = 0.f;
    }
    if (t < 64) we2s[t >> 3][t & 7] = we_w2[t];
    if (t < 8)  web2[t] = we_b2[t];
    WSYNC();

    const f32x4_t fzero = {0.f, 0.f, 0.f, 0.f};

    // ---- h0 (pb MLP hidden): own 16 rows x 4 cols ----
    #pragma unroll
    for (int m = 0; m < 16; ++m) {
        float4 p = *(const float4*)&posA[R0 + m][0];
        float h0 = fmaxf(p.x * cb[0].x + p.y * cb[0].y + p.z * cb[0].z + cb[0].w, 0.f);
        float h1 = fmaxf(p.x * cb[1].x + p.y * cb[1].y + p.z * cb[1].z + cb[1].w, 0.f);
        float h2 = fmaxf(p.x * cb[2].x + p.y * cb[2].y + p.z * cb[2].z + cb[2].w, 0.f);
        float h3 = fmaxf(p.x * cb[3].x + p.y * cb[3].y + p.z * cb[3].z + cb[3].w, 0.f);
        *(uint2*)&bufR[R0 + m][hc] = make_uint2(f2bpk(h0, h1), f2bpk(h2, h3));
    }
    __syncthreads();                           // B1

    // ---- pass0 MFMA (cooperative M=64, wave N-band): peb ----
    f32x4_t acc[4][4];
    for (int a = 0; a < 4; ++a) for (int mt = 0; mt < 4; ++mt) acc[a][mt] = fzero;
    #pragma unroll
    for (int kk = 0; kk < 8; ++kk) {
        bf16x8_t afr[4];
        #pragma unroll
        for (int mt = 0; mt < 4; ++mt)
            afr[mt] = *(const bf16x8_t*)&bufR[mt * 16 + ln15][kk * 32 + quad * 8];
        #pragma unroll
        for (int ntl = 0; ntl < 4; ++ntl) {
            int nt = w * 4 + ntl;
            bf16x8_t bfr = *(const bf16x8_t*)(pbw2F + ((nt * 8 + kk) * 64 + lane) * 8);
            #pragma unroll
            for (int mt = 0; mt < 4; ++mt)
                acc[ntl][mt] = __builtin_amdgcn_mfma_f32_16x16x32_bf16(afr[mt], bfr, acc[ntl][mt], 0, 0, 0);
        }
    }
    __syncthreads();                           // B2 (h0 reads done)

    // peb epilogue -> bufP
    #pragma unroll
    for (int ntl = 0; ntl < 4; ++ntl) {
        int c = (w * 4 + ntl) * 16 + ln15;
        float bbv = pb_b2[c];
        for (int mt = 0; mt < 4; ++mt)
            for (int r = 0; r < 4; r += 2) {
                unsigned int pk = f2bpk(acc[ntl][mt][r] + bbv, acc[ntl][mt][r + 1] + bbv);
                bufP[mt * 16 + quad * 4 + r][c]     = (unsigned short)pk;
                bufP[mt * 16 + quad * 4 + r + 1][c] = (unsigned short)(pk >> 16);
            }
    }
    // h1 (pm MLP hidden) -> bufR
    #pragma unroll
    for (int m = 0; m < 16; ++m) {
        float4 p = *(const float4*)&posA[R0 + m][0];
        float h0 = fmaxf(p.x * cm[0].x + p.y * cm[0].y + p.z * cm[0].z + cm[0].w, 0.f);
        float h1 = fmaxf(p.x * cm[1].x + p.y * cm[1].y + p.z * cm[1].z + cm[1].w, 0.f);
        float h2 = fmaxf(p.x * cm[2].x + p.y * cm[2].y + p.z * cm[2].z + cm[2].w, 0.f);
        float h3 = fmaxf(p.x * cm[3].x + p.y * cm[3].y + p.z * cm[3].z + cm[3].w, 0.f);
        *(uint2*)&bufR[R0 + m][hc] = make_uint2(f2bpk(h0, h1), f2bpk(h2, h3));
    }
    __syncthreads();                           // B3

    // ---- pass1 MFMA: pem ----
    for (int a = 0; a < 4; ++a) for (int mt = 0; mt < 4; ++mt) acc[a][mt] = fzero;
    #pragma unroll
    for (int kk = 0; kk < 8; ++kk) {
        bf16x8_t afr[4];
        #pragma unroll
        for (int mt = 0; mt < 4; ++mt)
            afr[mt] = *(const bf16x8_t*)&bufR[mt * 16 + ln15][kk * 32 + quad * 8];
        #pragma unroll
        for (int ntl = 0; ntl < 4; ++ntl) {
            int nt = w * 4 + ntl;
            bf16x8_t bfr = *(const bf16x8_t*)(pmw2F + ((nt * 8 + kk) * 64 + lane) * 8);
            #pragma unroll
            for (int mt = 0; mt < 4; ++mt)
                acc[ntl][mt] = __builtin_amdgcn_mfma_f32_16x16x32_bf16(afr[mt], bfr, acc[ntl][mt], 0, 0, 0);
        }
    }
    __syncthreads();                           // B4 (h1 reads done)

    // pem epilogue -> bufR
    #pragma unroll
    for (int ntl = 0; ntl < 4; ++ntl) {
        int c = (w * 4 + ntl) * 16 + ln15;
        float bbv = pm_b2[c];
        for (int mt = 0; mt < 4; ++mt)
            for (int r = 0; r < 4; r += 2) {
                unsigned int pk = f2bpk(acc[ntl][mt][r] + bbv, acc[ntl][mt][r + 1] + bbv);
                bufR[mt * 16 + quad * 4 + r][c]     = (unsigned short)pk;
                bufR[mt * 16 + quad * 4 + r + 1][c] = (unsigned short)(pk >> 16);
            }
    }
    __syncthreads();                           // B5 (pem/peb visible)

    // ---- relation + logits fused, in-register A-frags (per wave) ----
    {
        const bf16x8_t bz = {0, 0, 0, 0, 0, 0, 0, 0};
        f32x4_t lacc = fzero;
        #pragma unroll
        for (int kk = 0; kk < 8; ++kk) {
            int cb8 = kk * 32 + quad * 8;
            uint4 pm4 = *(const uint4*)&bufR[R0 + ln15][cb8];
            uint4 pb4 = *(const uint4*)&bufP[R0 + ln15][cb8];
            uint4 q4  = *(const uint4*)(qm + Pg * 256 + cb8);
            union { uint4 u; bf16x8_t v; } rr;
            rr.u.x = relpair(kpre[kk].x, q4.x, pm4.x, pb4.x);
            rr.u.y = relpair(kpre[kk].y, q4.y, pm4.y, pb4.y);
            rr.u.z = relpair(kpre[kk].z, q4.z, pm4.z, pb4.z);
            rr.u.w = relpair(kpre[kk].w, q4.w, pm4.w, pb4.w);
            bf16x8_t bfr = bz;
            if (ln15 < 8) bfr = *(const bf16x8_t*)(we1TF + ln15 * 256 + cb8);
            lacc = __builtin_amdgcn_mfma_f32_16x16x32_bf16(rr.v, bfr, lacc, 0, 0, 0);
        }
        if (ln15 < 8) {
            #pragma unroll
            for (int r = 0; r < 4; ++r)
                us_[R0 + quad * 4 + r][ln15] = fmaxf(lacc[r] * swe_r + dwe_r, 0.f);
        }
    }
    WSYNC();

    // ---- logits2 = u @ we_w2 + we_b2 (lanes<16, s=lane) ----
    if (lane < 16) {
        float uv[8], l[8];
        #pragma unroll
        for (int gp = 0; gp < 8; ++gp) uv[gp] = us_[R0 + lane][gp];
        #pragma unroll
        for (int g = 0; g < 8; ++g) {
            float x = web2[g];
            for (int gp = 0; gp < 8; ++gp) x += uv[gp] * we2s[gp][g];
            l[g] = x;
        }
        #pragma unroll
        for (int g = 0; g < 8; ++g) us_[R0 + lane][g] = l[g];
    }
    WSYNC();

    // ---- softmax over s (lanes<8, g=lane) ----
    if (lane < 8) {
        int g = lane;
        float mx = -1e30f;
        for (int s = 0; s < 16; ++s) mx = fmaxf(mx, us_[R0 + s][g]);
        float e[16], sum = 0.f;
        for (int s = 0; s < 16; ++s) { e[s] = __expf(us_[R0 + s][g] - mx); sum += e[s]; }
        float inv = 1.f / sum;
        for (int s = 0; s < 16; ++s) us_[R0 + s][g] = e[s] * inv;
    }
    WSYNC();

    // ---- output: out[Pg][c5] = sum_s w[s][g] * (v_g + peb) ----
    {
        int c5 = lane * 4, g = lane >> 3;
        float a0 = 0.f, a1 = 0.f, a2 = 0.f, a3 = 0.f;
        #pragma unroll
        for (int s = 0; s < 16; ++s) {
            int rv = rowg_[R0 + s];
            float wv_ = us_[R0 + s][g];
            uint2 v4 = *(const uint2*)(vm + rv * 256 + c5);
            uint2 p4 = *(const uint2*)&bufP[R0 + s][c5];
            a0 += wv_ * (blo(v4.x) + blo(p4.x));
            a1 += wv_ * (bhi(v4.x) + bhi(p4.x));
            a2 += wv_ * (blo(v4.y) + blo(p4.y));
            a3 += wv_ * (bhi(v4.y) + bhi(p4.y));
        }
        *(float4*)(out + (size_t)Pg * 256 + c5) = make_float4(a0, a1, a2, a3);
    }
}

// ---------------------------------------------------------------------------
extern "C" void kernel_launch(void* const* d_in, const int* in_sizes, int n_in,
                              void* d_out, int out_size, void* d_ws, size_t ws_size,
                              hipStream_t stream)
{
    const float* feats  = (const float*)d_in[0];
    const float* coords = (const float*)d_in[1];
    const int*   index  = (const int*)d_in[2];
    const float* wq     = (const float*)d_in[3];
    const float* bq     = (const float*)d_in[4];
    const float* bnq    = (const float*)d_in[5];
    const float* wk     = (const float*)d_in[6];
    const float* bk     = (const float*)d_in[7];
    const float* bnk    = (const float*)d_in[8];
    const float* wv     = (const float*)d_in[9];
    const float* bv     = (const float*)d_in[10];
    const float* pm_w1  = (const float*)d_in[11];
    const float* pm_b1  = (const float*)d_in[12];
    const float* pm_bn  = (const float*)d_in[13];
    const float* pm_w2  = (const float*)d_in[14];
    const float* pm_b2  = (const float*)d_in[15];
    const float* pb_w1  = (const float*)d_in[16];
    const float* pb_b1  = (const float*)d_in[17];
    const float* pb_bn  = (const float*)d_in[18];
    const float* pb_w2  = (const float*)d_in[19];
    const float* pb_b2  = (const float*)d_in[20];
    const float* we_w1  = (const float*)d_in[21];
    const float* we_b1  = (const float*)d_in[22];
    const float* we_bn  = (const float*)d_in[23];
    const float* we_w2  = (const float*)d_in[24];
    const float* we_b2  = (const float*)d_in[25];

    unsigned short* qkv   = (unsigned short*)d_ws;                    // 12.58 MB
    unsigned short* wsT   = qkv + (size_t)3 * 8192 * 256;             // 640 KB
    float*          W4    = (float*)(wsT + 5 * 65536);                // 8 KB
    unsigned short* we1TF = (unsigned short*)(W4 + 2048);             // 4 KB

    const size_t need = (size_t)13238272 + 8192 + 4096;
    if (ws_size < need) {
        hipMemsetAsync(d_out, 0, (size_t)out_size * 4, stream);
        return;
    }

    k_prep<<<162,  256, 0, stream>>>(wq, wk, wv, pm_w2, pb_w2,
                                     pm_w1, pm_b1, pm_bn,
                                     pb_w1, pb_b1, pb_bn,
                                     we_w1, wsT, W4, we1TF);
    k_qkv <<<768,  256, 0, stream>>>(feats, wsT, bq, bnq, bk, bnk, bv, qkv);
    k_main<<<2048, 256, 0, stream>>>(coords, index,
                                     qkv,
                                     qkv + (size_t)8192 * 256,
                                     qkv + (size_t)2 * 8192 * 256,
                                     wsT + 3 * 65536,
                                     wsT + 4 * 65536,
                                     W4, we1TF,
                                     pm_b2, pb_b2,
                                     we_b1, we_bn, we_w2, we_b2,
                                     (float*)d_out);
}